// Round 5
// baseline (252.760 us; speedup 1.0000x reference)
//
#include <hip/hip_runtime.h>
#include <hip/hip_bf16.h>

typedef unsigned short u16;
typedef __bf16 bf16x8 __attribute__((ext_vector_type(8)));
typedef float f32x4 __attribute__((ext_vector_type(4)));

#define S_LEN 2048
#define HID 2048
#define NH 32
#define NKV 8
#define HD 64

__device__ inline u16 f2bf(float x) {
    unsigned int u = __float_as_uint(x);
    unsigned int r = (u + 0x7fffu + ((u >> 16) & 1u)) >> 16;
    return (u16)r;
}
__device__ inline float bf2f(u16 u) {
    return __uint_as_float(((unsigned int)u) << 16);
}

__device__ inline void gload_lds16(const u16* g, u16* l) {
    __builtin_amdgcn_global_load_lds((const __attribute__((address_space(1))) unsigned int*)g,
                                     (__attribute__((address_space(3))) unsigned int*)l, 16, 0, 0);
}

// ---------------- fp32 -> bf16 convert, all 5 tensors in one launch ----------------
__global__ void cvt_all(const float* __restrict__ h, const float* __restrict__ wq,
                        const float* __restrict__ wk, const float* __restrict__ wv,
                        const float* __restrict__ wo,
                        u16* __restrict__ hb, u16* __restrict__ wqkv, u16* __restrict__ wob) {
    int i = blockIdx.x * blockDim.x + threadIdx.x;   // float4 index, total 3670016
    const float* src; u16* dst; int o;
    if (i < 1048576)      { src = h;  dst = hb;   o = i; }
    else if (i < 2097152) { src = wq; dst = wqkv; o = i - 1048576; }
    else if (i < 2359296) { src = wk; dst = wqkv + (size_t)2048 * 2048; o = i - 2097152; }
    else if (i < 2621440) { src = wv; dst = wqkv + (size_t)2560 * 2048; o = i - 2359296; }
    else                  { src = wo; dst = wob;  o = i - 2621440; }
    float4 v = ((const float4*)src)[o];
    ushort4 u;
    u.x = f2bf(v.x); u.y = f2bf(v.y); u.z = f2bf(v.z); u.w = f2bf(v.w);
    ((ushort4*)dst)[o] = u;
}

// ---------------- GEMM: C[M,N] = A[M,K] * B[N,K]^T (both bf16 row-major) ----------------
// mode 1: store fp32 row-major (ldc)
// mode 3: fused QKV epilogue: col<2048 -> qbuf, <2560 -> kbuf, else vT transposed
__global__ __launch_bounds__(256) void gemm_bt(const u16* __restrict__ A,
                                               const u16* __restrict__ B,
                                               void* __restrict__ Cv,
                                               int K_, int mode, int ldc) {
    __shared__ u16 As[128 * 32];
    __shared__ u16 Bs[128 * 32];
    const int t = threadIdx.x;
    // XCD-aware bijective swizzle (nwg % 8 == 0 for both call sites)
    const int nwg = gridDim.x * gridDim.y;
    const int orig = blockIdx.y * gridDim.x + blockIdx.x;
    const int wgid = (orig & 7) * (nwg >> 3) + (orig >> 3);
    const int bm = wgid % gridDim.x, bn = wgid / gridDim.x;
    const int lane = t & 63, w = t >> 6;
    const int wr = (w >> 1) * 64, wc = (w & 1) * 64;
    const int g = lane >> 4, r16 = lane & 15;
    f32x4 acc[4][4] = {};

    const int srow = w * 32 + (lane >> 2);
    const int scol = (lane & 3) * 8;
    const u16* Ap = A + (size_t)(bm * 128 + srow) * K_ + scol;
    const u16* Bp = B + (size_t)(bn * 128 + srow) * K_ + scol;
    u16* AsW = &As[w * 1024];
    u16* BsW = &Bs[w * 1024];

    for (int kt = 0; kt < K_; kt += 32) {
        __syncthreads();
        gload_lds16(Ap + kt, AsW);
        gload_lds16(Ap + kt + (size_t)16 * K_, AsW + 512);
        gload_lds16(Bp + kt, BsW);
        gload_lds16(Bp + kt + (size_t)16 * K_, BsW + 512);
        __syncthreads();
        bf16x8 af[4], bfr[4];
#pragma unroll
        for (int i = 0; i < 4; i++) af[i] = *(const bf16x8*)(&As[(wr + i * 16 + r16) * 32 + g * 8]);
#pragma unroll
        for (int j = 0; j < 4; j++) bfr[j] = *(const bf16x8*)(&Bs[(wc + j * 16 + r16) * 32 + g * 8]);
#pragma unroll
        for (int i = 0; i < 4; i++)
#pragma unroll
            for (int j = 0; j < 4; j++)
                acc[i][j] = __builtin_amdgcn_mfma_f32_16x16x32_bf16(af[i], bfr[j], acc[i][j], 0, 0, 0);
    }

    u16* qb_ = (u16*)Cv;
    u16* kb_ = qb_ + (size_t)2048 * 2048;
    u16* vt_ = kb_ + (size_t)512 * 2048;
#pragma unroll
    for (int i = 0; i < 4; i++)
#pragma unroll
        for (int j = 0; j < 4; j++)
#pragma unroll
            for (int r = 0; r < 4; r++) {
                int row = bm * 128 + wr + i * 16 + g * 4 + r;
                int col = bn * 128 + wc + j * 16 + r16;
                float v = acc[i][j][r];
                if (mode == 1) {
                    ((float*)Cv)[(size_t)row * ldc + col] = v;
                } else {
                    if (col < 2048)      qb_[(size_t)row * 2048 + col] = f2bf(v);
                    else if (col < 2560) kb_[(size_t)row * 512 + (col - 2048)] = f2bf(v);
                    else                 vt_[(size_t)(col - 2560) * 2048 + row] = f2bf(v);
                }
            }
}

// ---------------- RoPE (in-place; q additionally pre-scaled by 0.125*log2e) ----------------
__global__ void rope_kernel(u16* __restrict__ qb, u16* __restrict__ kb,
                            const float* __restrict__ cosp, const float* __restrict__ sinp) {
    const float QSCL = 0.125f * 1.44269504f;
    int s = blockIdx.x;
    for (int it = threadIdx.x; it < (NH + NKV) * 32; it += blockDim.x) {
        int head = it >> 5, i = it & 31;
        bool isq = head < NH;
        u16* base = isq ? qb + (size_t)s * (NH * HD) + head * HD
                        : kb + (size_t)s * (NKV * HD) + (head - NH) * HD;
        float scl = isq ? QSCL : 1.0f;
        float x1 = bf2f(base[i]), x2 = bf2f(base[i + 32]);
        float c1 = cosp[s * HD + i], s1 = sinp[s * HD + i];
        float c2 = cosp[s * HD + i + 32], s2 = sinp[s * HD + i + 32];
        base[i] = f2bf((x1 * c1 - x2 * s1) * scl);
        base[i + 32] = f2bf((x2 * c2 + x1 * s2) * scl);
    }
}

// ---------------- Flash attention (causal, GQA) ----------------
// 1 wave/block, 32 q-rows/wave, KV tile = 128 cols/iteration. No setprio;
// explicit lgkmcnt fence between P stores and PV reads.
__global__ __launch_bounds__(64) void attn_kernel(const u16* __restrict__ q,
                                                  const u16* __restrict__ k,
                                                  const u16* __restrict__ vT,
                                                  u16* __restrict__ attn) {
    __shared__ u16 P[2][16][136];  // [frag][qrow][kcol]
    const int bid = blockIdx.x;
    const int h = bid & 31, qblk = bid >> 5;   // qblk 0..63, 32 rows each
    const int lane = threadIdx.x & 63;
    const int g = lane >> 4, r16 = lane & 15;
    const int kvh = h >> 2;
    const int qrow0 = qblk * 32;

    bf16x8 qf[2][2];
#pragma unroll
    for (int fi = 0; fi < 2; fi++)
#pragma unroll
        for (int d = 0; d < 2; d++)
            qf[fi][d] = *(const bf16x8*)(q + (size_t)(qrow0 + fi * 16 + r16) * (NH * HD) + h * HD + d * 32 + g * 8);

    float m_run[2][4], l_run[2][4];
    f32x4 o[2][4] = {};
#pragma unroll
    for (int fi = 0; fi < 2; fi++)
#pragma unroll
        for (int r = 0; r < 4; r++) { m_run[fi][r] = -1e30f; l_run[fi][r] = 0.f; }

    const int last = (qrow0 >> 7) << 7;   // last 128-wide KV tile start
    for (int kv = 0; kv <= last; kv += 128) {
        const bool diag = (kv == last);
        f32x4 sacc[2][8] = {};
        // ---- QK^T in two 64-col halves (caps live K regs at 32) ----
#pragma unroll
        for (int half = 0; half < 2; half++) {
            bf16x8 kf[4][2];
#pragma unroll
            for (int s4 = 0; s4 < 4; s4++)
#pragma unroll
                for (int d = 0; d < 2; d++)
                    kf[s4][d] = *(const bf16x8*)(k + (size_t)(kv + half * 64 + s4 * 16 + r16) * (NKV * HD) + kvh * HD + d * 32 + g * 8);
#pragma unroll
            for (int s4 = 0; s4 < 4; s4++)
#pragma unroll
                for (int fi = 0; fi < 2; fi++)
#pragma unroll
                    for (int d = 0; d < 2; d++)
                        sacc[fi][half * 4 + s4] = __builtin_amdgcn_mfma_f32_16x16x32_bf16(qf[fi][d], kf[s4][d], sacc[fi][half * 4 + s4], 0, 0, 0);
        }
        // ---- V loads issued early: latency hides under softmax ----
        bf16x8 vf[4][4];
#pragma unroll
        for (int kq = 0; kq < 4; kq++)
#pragma unroll
            for (int dblk = 0; dblk < 4; dblk++)
                vf[kq][dblk] = *(const bf16x8*)(vT + (size_t)(kvh * HD + dblk * 16 + r16) * S_LEN + kv + kq * 32 + g * 8);
        // ---- causal mask (diagonal super-tile only) ----
        if (diag) {
#pragma unroll
            for (int fi = 0; fi < 2; fi++)
#pragma unroll
                for (int sub = 0; sub < 8; sub++)
#pragma unroll
                    for (int r = 0; r < 4; r++) {
                        int col = kv + sub * 16 + r16;
                        int row = qrow0 + fi * 16 + g * 4 + r;
                        if (col > row) sacc[fi][sub][r] = -1e30f;
                    }
        }
        // ---- softmax per fragment ----
#pragma unroll
        for (int fi = 0; fi < 2; fi++) {
            float mt[4];
#pragma unroll
            for (int r = 0; r < 4; r++) {
                float a = fmaxf(fmaxf(sacc[fi][0][r], sacc[fi][1][r]), fmaxf(sacc[fi][2][r], sacc[fi][3][r]));
                float b = fmaxf(fmaxf(sacc[fi][4][r], sacc[fi][5][r]), fmaxf(sacc[fi][6][r], sacc[fi][7][r]));
                mt[r] = fmaxf(a, b);
            }
#pragma unroll
            for (int r = 0; r < 4; r++) {
                mt[r] = fmaxf(mt[r], __shfl_xor(mt[r], 1));
                mt[r] = fmaxf(mt[r], __shfl_xor(mt[r], 2));
                mt[r] = fmaxf(mt[r], __shfl_xor(mt[r], 4));
                mt[r] = fmaxf(mt[r], __shfl_xor(mt[r], 8));
            }
            // defer-max: skip rescale when running max doesn't grow (exact, deterministic)
            bool grow = (mt[0] > m_run[fi][0]) | (mt[1] > m_run[fi][1]) |
                        (mt[2] > m_run[fi][2]) | (mt[3] > m_run[fi][3]);
            if (__any(grow)) {
#pragma unroll
                for (int r = 0; r < 4; r++) {
                    float mn = fmaxf(m_run[fi][r], mt[r]);
                    float alpha = exp2f(m_run[fi][r] - mn);
                    m_run[fi][r] = mn;
                    l_run[fi][r] *= alpha;
#pragma unroll
                    for (int dblk = 0; dblk < 4; dblk++) o[fi][dblk][r] *= alpha;
                }
            }
            float ps[4] = {0.f, 0.f, 0.f, 0.f};
#pragma unroll
            for (int sub = 0; sub < 8; sub++)
#pragma unroll
                for (int r = 0; r < 4; r++) {
                    float p = exp2f(sacc[fi][sub][r] - m_run[fi][r]);
                    sacc[fi][sub][r] = p;
                    ps[r] += p;
                }
#pragma unroll
            for (int r = 0; r < 4; r++) {
                ps[r] += __shfl_xor(ps[r], 1);
                ps[r] += __shfl_xor(ps[r], 2);
                ps[r] += __shfl_xor(ps[r], 4);
                ps[r] += __shfl_xor(ps[r], 8);
                l_run[fi][r] += ps[r];
            }
            // P (C-layout) -> LDS
#pragma unroll
            for (int sub = 0; sub < 8; sub++)
#pragma unroll
                for (int r = 0; r < 4; r++)
                    P[fi][g * 4 + r][sub * 16 + r16] = f2bf(sacc[fi][sub][r]);
        }
        // fence: all P stores committed to LDS before any PV read; pin ordering
        asm volatile("s_waitcnt lgkmcnt(0)" ::: "memory");
        __builtin_amdgcn_sched_barrier(0);
        // ---- PV: 32 MFMA ----
#pragma unroll
        for (int fi = 0; fi < 2; fi++)
#pragma unroll
            for (int kq = 0; kq < 4; kq++) {
                bf16x8 pf = *(const bf16x8*)(&P[fi][r16][kq * 32 + g * 8]);
#pragma unroll
                for (int dblk = 0; dblk < 4; dblk++)
                    o[fi][dblk] = __builtin_amdgcn_mfma_f32_16x16x32_bf16(pf, vf[kq][dblk], o[fi][dblk], 0, 0, 0);
            }
    }
#pragma unroll
    for (int fi = 0; fi < 2; fi++)
#pragma unroll
        for (int dblk = 0; dblk < 4; dblk++)
#pragma unroll
            for (int r = 0; r < 4; r++) {
                float val = o[fi][dblk][r] / l_run[fi][r];
                attn[(size_t)(qrow0 + fi * 16 + g * 4 + r) * (NH * HD) + h * HD + dblk * 16 + r16] = f2bf(val);
            }
}

extern "C" void kernel_launch(void* const* d_in, const int* in_sizes, int n_in,
                              void* d_out, int out_size, void* d_ws, size_t ws_size,
                              hipStream_t stream) {
    const float* hidden = (const float*)d_in[0];
    const float* Wq = (const float*)d_in[1];
    const float* Wk = (const float*)d_in[2];
    const float* Wv = (const float*)d_in[3];
    const float* Wo = (const float*)d_in[4];
    const float* cosp = (const float*)d_in[5];
    const float* sinp = (const float*)d_in[6];
    float* out = (float*)d_out;

    char* ws = (char*)d_ws;
    u16* hb   = (u16*)(ws);                        // 8 MB  [2048,2048]
    u16* wqkv = (u16*)(ws + ((size_t)8 << 20));    // 12 MB [3072,2048] (Wq;Wk;Wv)
    u16* wob  = (u16*)(ws + ((size_t)20 << 20));   // 8 MB  [2048,2048]
    u16* qbuf = (u16*)(ws + ((size_t)28 << 20));   // 8 MB  [2048,2048]  (kbuf, vT follow contiguously)
    u16* kbuf = qbuf + (size_t)2048 * 2048;        // 2 MB  [2048,512]
    u16* vT   = kbuf + (size_t)512 * 2048;         // 2 MB  [512,2048]
    u16* attn = (u16*)(ws + ((size_t)40 << 20));   // 8 MB  [2048,2048]

    // single fused fp32->bf16 conversion launch
    cvt_all<<<14336, 256, 0, stream>>>(hidden, Wq, Wk, Wv, Wo, hb, wqkv, wob);

    // fused QKV projection: [2048,2048] x [3072,2048]^T
    gemm_bt<<<dim3(16, 24), 256, 0, stream>>>(hb, wqkv, qbuf, HID, 3, 0);

    // rope on q (pre-scaled), k
    rope_kernel<<<S_LEN, 256, 0, stream>>>(qbuf, kbuf, cosp, sinp);

    // flash attention: 1 wave/block, 32 q-rows/wave, KVBLK=128
    attn_kernel<<<S_LEN / 32 * NH, 64, 0, stream>>>(qbuf, kbuf, vT, attn);

    // output projection -> fp32
    gemm_bt<<<dim3(16, 16), 256, 0, stream>>>(attn, wob, out, HID, 1, HID);

    (void)in_sizes; (void)n_in; (void)out_size; (void)ws_size;
}

// Round 6
// 217.599 us; speedup vs baseline: 1.1616x; 1.1616x over previous
//
#include <hip/hip_runtime.h>
#include <hip/hip_bf16.h>

typedef unsigned short u16;
typedef __bf16 bf16x8 __attribute__((ext_vector_type(8)));
typedef float f32x4 __attribute__((ext_vector_type(4)));

#define S_LEN 2048
#define HID 2048
#define NH 32
#define NKV 8
#define HD 64

__device__ inline u16 f2bf(float x) {
    unsigned int u = __float_as_uint(x);
    unsigned int r = (u + 0x7fffu + ((u >> 16) & 1u)) >> 16;
    return (u16)r;
}
__device__ inline float bf2f(u16 u) {
    return __uint_as_float(((unsigned int)u) << 16);
}

__device__ inline void gload_lds16(const u16* g, u16* l) {
    __builtin_amdgcn_global_load_lds((const __attribute__((address_space(1))) unsigned int*)g,
                                     (__attribute__((address_space(3))) unsigned int*)l, 16, 0, 0);
}

// ---------------- fp32 -> bf16 convert, all 5 tensors in one launch ----------------
__global__ void cvt_all(const float* __restrict__ h, const float* __restrict__ wq,
                        const float* __restrict__ wk, const float* __restrict__ wv,
                        const float* __restrict__ wo,
                        u16* __restrict__ hb, u16* __restrict__ wqkv, u16* __restrict__ wob) {
    int i = blockIdx.x * blockDim.x + threadIdx.x;   // float4 index, total 3670016
    const float* src; u16* dst; int o;
    if (i < 1048576)      { src = h;  dst = hb;   o = i; }
    else if (i < 2097152) { src = wq; dst = wqkv; o = i - 1048576; }
    else if (i < 2359296) { src = wk; dst = wqkv + (size_t)2048 * 2048; o = i - 2097152; }
    else if (i < 2621440) { src = wv; dst = wqkv + (size_t)2560 * 2048; o = i - 2359296; }
    else                  { src = wo; dst = wob;  o = i - 2621440; }
    float4 v = ((const float4*)src)[o];
    ushort4 u;
    u.x = f2bf(v.x); u.y = f2bf(v.y); u.z = f2bf(v.z); u.w = f2bf(v.w);
    ((ushort4*)dst)[o] = u;
}

// ---------------- GEMM: C[M,N] = A[M,K] * B[N,K]^T (both bf16 row-major) ----------------
// mode 1: store fp32 row-major (ldc)
// mode 3: fused QKV epilogue with RoPE: col<2048 -> qbuf (rope, pre-scaled),
//         <2560 -> kbuf (rope), else vT transposed
__global__ __launch_bounds__(256) void gemm_bt(const u16* __restrict__ A,
                                               const u16* __restrict__ B,
                                               void* __restrict__ Cv,
                                               int K_, int mode, int ldc,
                                               const float* __restrict__ cosp,
                                               const float* __restrict__ sinp) {
    __shared__ u16 As[128 * 32];
    __shared__ u16 Bs[128 * 32];
    const int t = threadIdx.x;
    // XCD-aware bijective swizzle (nwg % 8 == 0 for both call sites)
    const int nwg = gridDim.x * gridDim.y;
    const int orig = blockIdx.y * gridDim.x + blockIdx.x;
    const int wgid = (orig & 7) * (nwg >> 3) + (orig >> 3);
    const int bm = wgid % gridDim.x, bn = wgid / gridDim.x;
    const int lane = t & 63, w = t >> 6;
    const int wr = (w >> 1) * 64, wc = (w & 1) * 64;
    const int g = lane >> 4, r16 = lane & 15;
    f32x4 acc[4][4] = {};

    const int srow = w * 32 + (lane >> 2);
    const int scol = (lane & 3) * 8;
    const u16* Ap = A + (size_t)(bm * 128 + srow) * K_ + scol;
    const u16* Bp = B + (size_t)(bn * 128 + srow) * K_ + scol;
    u16* AsW = &As[w * 1024];
    u16* BsW = &Bs[w * 1024];

    for (int kt = 0; kt < K_; kt += 32) {
        __syncthreads();
        gload_lds16(Ap + kt, AsW);
        gload_lds16(Ap + kt + (size_t)16 * K_, AsW + 512);
        gload_lds16(Bp + kt, BsW);
        gload_lds16(Bp + kt + (size_t)16 * K_, BsW + 512);
        __syncthreads();
        bf16x8 af[4], bfr[4];
#pragma unroll
        for (int i = 0; i < 4; i++) af[i] = *(const bf16x8*)(&As[(wr + i * 16 + r16) * 32 + g * 8]);
#pragma unroll
        for (int j = 0; j < 4; j++) bfr[j] = *(const bf16x8*)(&Bs[(wc + j * 16 + r16) * 32 + g * 8]);
#pragma unroll
        for (int i = 0; i < 4; i++)
#pragma unroll
            for (int j = 0; j < 4; j++)
                acc[i][j] = __builtin_amdgcn_mfma_f32_16x16x32_bf16(af[i], bfr[j], acc[i][j], 0, 0, 0);
    }

    u16* qb_ = (u16*)Cv;
    u16* kb_ = qb_ + (size_t)2048 * 2048;
    u16* vt_ = kb_ + (size_t)512 * 2048;
    if (mode == 1) {
#pragma unroll
        for (int i = 0; i < 4; i++)
#pragma unroll
            for (int j = 0; j < 4; j++)
#pragma unroll
                for (int r = 0; r < 4; r++) {
                    int row = bm * 128 + wr + i * 16 + g * 4 + r;
                    int col = bn * 128 + wc + j * 16 + r16;
                    ((float*)Cv)[(size_t)row * ldc + col] = acc[i][j][r];
                }
    } else {
        const int cbase = bn * 128 + wc;   // 64-aligned => wave span = one head
        if (cbase < 2560) {
            // q or k region: fused RoPE on fp32 accumulators (exact pre-round)
            const float scl = (cbase < 2048) ? 0.125f * 1.44269504f : 1.0f;
#pragma unroll
            for (int i = 0; i < 4; i++)
#pragma unroll
                for (int r = 0; r < 4; r++) {
                    int row = bm * 128 + wr + i * 16 + g * 4 + r;
#pragma unroll
                    for (int j = 0; j < 2; j++) {
                        int c0 = cbase + j * 16 + r16;
                        int iin = c0 & 63;                 // in-head dim, < 32
                        float x1 = acc[i][j][r], x2 = acc[i][j + 2][r];
                        float cA = cosp[row * 64 + iin],      sA = sinp[row * 64 + iin];
                        float cB = cosp[row * 64 + iin + 32], sB = sinp[row * 64 + iin + 32];
                        u16 o1 = f2bf((x1 * cA - x2 * sA) * scl);
                        u16 o2 = f2bf((x2 * cB + x1 * sB) * scl);
                        if (cbase < 2048) {
                            qb_[(size_t)row * 2048 + c0] = o1;
                            qb_[(size_t)row * 2048 + c0 + 32] = o2;
                        } else {
                            kb_[(size_t)row * 512 + (c0 - 2048)] = o1;
                            kb_[(size_t)row * 512 + (c0 - 2048 + 32)] = o2;
                        }
                    }
                }
        } else {
#pragma unroll
            for (int i = 0; i < 4; i++)
#pragma unroll
                for (int j = 0; j < 4; j++)
#pragma unroll
                    for (int r = 0; r < 4; r++) {
                        int row = bm * 128 + wr + i * 16 + g * 4 + r;
                        int col = cbase + j * 16 + r16;
                        vt_[(size_t)(col - 2560) * 2048 + row] = f2bf(acc[i][j][r]);
                    }
        }
    }
}

// ---------------- Flash attention (causal, GQA) ----------------
// 1 wave/block, 32 q-rows/wave, KV tile = 128. Barrier-free per-wave P LDS
// (R3-proven: same-wave DS ordering + compiler lgkmcnt). No setprio, no fences.
__global__ __launch_bounds__(64) void attn_kernel(const u16* __restrict__ q,
                                                  const u16* __restrict__ k,
                                                  const u16* __restrict__ vT,
                                                  u16* __restrict__ attn) {
    __shared__ u16 P[2][16][136];  // [frag][qrow][kcol]
    const int bid = blockIdx.x;
    const int h = bid & 31;
    const int qblk = 63 - (bid >> 5);   // heaviest (most KV tiles) blocks dispatch first
    const int lane = threadIdx.x & 63;
    const int g = lane >> 4, r16 = lane & 15;
    const int kvh = h >> 2;
    const int qrow0 = qblk * 32;

    bf16x8 qf[2][2];
#pragma unroll
    for (int fi = 0; fi < 2; fi++)
#pragma unroll
        for (int d = 0; d < 2; d++)
            qf[fi][d] = *(const bf16x8*)(q + (size_t)(qrow0 + fi * 16 + r16) * (NH * HD) + h * HD + d * 32 + g * 8);

    float m_run[2][4], l_run[2][4];
    f32x4 o[2][4] = {};
#pragma unroll
    for (int fi = 0; fi < 2; fi++)
#pragma unroll
        for (int r = 0; r < 4; r++) { m_run[fi][r] = -1e30f; l_run[fi][r] = 0.f; }

    const int last = (qrow0 >> 7) << 7;   // last 128-wide KV tile start
    for (int kv = 0; kv <= last; kv += 128) {
        const bool diag = (kv == last);
        f32x4 sacc[2][8] = {};
        // ---- QK^T in two 64-col halves (caps live K regs at 32) ----
#pragma unroll
        for (int half = 0; half < 2; half++) {
            bf16x8 kf[4][2];
#pragma unroll
            for (int s4 = 0; s4 < 4; s4++)
#pragma unroll
                for (int d = 0; d < 2; d++)
                    kf[s4][d] = *(const bf16x8*)(k + (size_t)(kv + half * 64 + s4 * 16 + r16) * (NKV * HD) + kvh * HD + d * 32 + g * 8);
#pragma unroll
            for (int s4 = 0; s4 < 4; s4++)
#pragma unroll
                for (int fi = 0; fi < 2; fi++)
#pragma unroll
                    for (int d = 0; d < 2; d++)
                        sacc[fi][half * 4 + s4] = __builtin_amdgcn_mfma_f32_16x16x32_bf16(qf[fi][d], kf[s4][d], sacc[fi][half * 4 + s4], 0, 0, 0);
        }
        // ---- V loads issued early: latency hides under softmax ----
        bf16x8 vf[4][4];
#pragma unroll
        for (int kq = 0; kq < 4; kq++)
#pragma unroll
            for (int dblk = 0; dblk < 4; dblk++)
                vf[kq][dblk] = *(const bf16x8*)(vT + (size_t)(kvh * HD + dblk * 16 + r16) * S_LEN + kv + kq * 32 + g * 8);
        // ---- causal mask (diagonal super-tile only) ----
        if (diag) {
#pragma unroll
            for (int fi = 0; fi < 2; fi++)
#pragma unroll
                for (int sub = 0; sub < 8; sub++)
#pragma unroll
                    for (int r = 0; r < 4; r++) {
                        int col = kv + sub * 16 + r16;
                        int row = qrow0 + fi * 16 + g * 4 + r;
                        if (col > row) sacc[fi][sub][r] = -1e30f;
                    }
        }
        // ---- softmax per fragment ----
#pragma unroll
        for (int fi = 0; fi < 2; fi++) {
            float mt[4];
#pragma unroll
            for (int r = 0; r < 4; r++) {
                float a = fmaxf(fmaxf(sacc[fi][0][r], sacc[fi][1][r]), fmaxf(sacc[fi][2][r], sacc[fi][3][r]));
                float b = fmaxf(fmaxf(sacc[fi][4][r], sacc[fi][5][r]), fmaxf(sacc[fi][6][r], sacc[fi][7][r]));
                mt[r] = fmaxf(a, b);
            }
#pragma unroll
            for (int r = 0; r < 4; r++) {
                mt[r] = fmaxf(mt[r], __shfl_xor(mt[r], 1));
                mt[r] = fmaxf(mt[r], __shfl_xor(mt[r], 2));
                mt[r] = fmaxf(mt[r], __shfl_xor(mt[r], 4));
                mt[r] = fmaxf(mt[r], __shfl_xor(mt[r], 8));
            }
            // defer-max: skip rescale when running max doesn't grow (exact, deterministic)
            bool grow = (mt[0] > m_run[fi][0]) | (mt[1] > m_run[fi][1]) |
                        (mt[2] > m_run[fi][2]) | (mt[3] > m_run[fi][3]);
            if (__any(grow)) {
#pragma unroll
                for (int r = 0; r < 4; r++) {
                    float mn = fmaxf(m_run[fi][r], mt[r]);
                    float alpha = exp2f(m_run[fi][r] - mn);
                    m_run[fi][r] = mn;
                    l_run[fi][r] *= alpha;
#pragma unroll
                    for (int dblk = 0; dblk < 4; dblk++) o[fi][dblk][r] *= alpha;
                }
            }
            float ps[4] = {0.f, 0.f, 0.f, 0.f};
#pragma unroll
            for (int sub = 0; sub < 8; sub++)
#pragma unroll
                for (int r = 0; r < 4; r++) {
                    float p = exp2f(sacc[fi][sub][r] - m_run[fi][r]);
                    sacc[fi][sub][r] = p;
                    ps[r] += p;
                }
#pragma unroll
            for (int r = 0; r < 4; r++) {
                ps[r] += __shfl_xor(ps[r], 1);
                ps[r] += __shfl_xor(ps[r], 2);
                ps[r] += __shfl_xor(ps[r], 4);
                ps[r] += __shfl_xor(ps[r], 8);
                l_run[fi][r] += ps[r];
            }
            // P (C-layout) -> LDS
#pragma unroll
            for (int sub = 0; sub < 8; sub++)
#pragma unroll
                for (int r = 0; r < 4; r++)
                    P[fi][g * 4 + r][sub * 16 + r16] = f2bf(sacc[fi][sub][r]);
        }
        // ---- PV: 32 MFMA (compiler inserts lgkmcnt for same-wave LDS dep) ----
#pragma unroll
        for (int fi = 0; fi < 2; fi++)
#pragma unroll
            for (int kq = 0; kq < 4; kq++) {
                bf16x8 pf = *(const bf16x8*)(&P[fi][r16][kq * 32 + g * 8]);
#pragma unroll
                for (int dblk = 0; dblk < 4; dblk++)
                    o[fi][dblk] = __builtin_amdgcn_mfma_f32_16x16x32_bf16(pf, vf[kq][dblk], o[fi][dblk], 0, 0, 0);
            }
    }
#pragma unroll
    for (int fi = 0; fi < 2; fi++)
#pragma unroll
        for (int dblk = 0; dblk < 4; dblk++)
#pragma unroll
            for (int r = 0; r < 4; r++) {
                float val = o[fi][dblk][r] / l_run[fi][r];
                attn[(size_t)(qrow0 + fi * 16 + g * 4 + r) * (NH * HD) + h * HD + dblk * 16 + r16] = f2bf(val);
            }
}

extern "C" void kernel_launch(void* const* d_in, const int* in_sizes, int n_in,
                              void* d_out, int out_size, void* d_ws, size_t ws_size,
                              hipStream_t stream) {
    const float* hidden = (const float*)d_in[0];
    const float* Wq = (const float*)d_in[1];
    const float* Wk = (const float*)d_in[2];
    const float* Wv = (const float*)d_in[3];
    const float* Wo = (const float*)d_in[4];
    const float* cosp = (const float*)d_in[5];
    const float* sinp = (const float*)d_in[6];
    float* out = (float*)d_out;

    char* ws = (char*)d_ws;
    u16* hb   = (u16*)(ws);                        // 8 MB  [2048,2048]
    u16* wqkv = (u16*)(ws + ((size_t)8 << 20));    // 12 MB [3072,2048] (Wq;Wk;Wv)
    u16* wob  = (u16*)(ws + ((size_t)20 << 20));   // 8 MB  [2048,2048]
    u16* qbuf = (u16*)(ws + ((size_t)28 << 20));   // 8 MB  [2048,2048]  (kbuf, vT follow contiguously)
    u16* kbuf = qbuf + (size_t)2048 * 2048;        // 2 MB  [2048,512]
    u16* vT   = kbuf + (size_t)512 * 2048;         // 2 MB  [512,2048]
    u16* attn = (u16*)(ws + ((size_t)40 << 20));   // 8 MB  [2048,2048]

    // single fused fp32->bf16 conversion launch
    cvt_all<<<14336, 256, 0, stream>>>(hidden, Wq, Wk, Wv, Wo, hb, wqkv, wob);

    // fused QKV projection + RoPE epilogue: [2048,2048] x [3072,2048]^T
    gemm_bt<<<dim3(16, 24), 256, 0, stream>>>(hb, wqkv, qbuf, HID, 3, 0, cosp, sinp);

    // flash attention: 1 wave/block, 32 q-rows/wave, KVBLK=128
    attn_kernel<<<S_LEN / 32 * NH, 64, 0, stream>>>(qbuf, kbuf, vT, attn);

    // output projection -> fp32
    gemm_bt<<<dim3(16, 16), 256, 0, stream>>>(attn, wob, out, HID, 1, HID, nullptr, nullptr);

    (void)in_sizes; (void)n_in; (void)out_size; (void)ws_size;
}